// Round 5
// baseline (154.804 us; speedup 1.0000x reference)
//
#include <hip/hip_runtime.h>

// Classwise ECE, probs [N=100000, C=1000] f32, labels [N] i32 -> scalar f32.
// R5: float4 loads (4 classes/thread, TC=1024 covers all C in one tile),
// correct-events fused as -65536 into the q16 LDS conf slots (no g_cor, no
// memset), 3 dispatches total (hist -> red1 -> red2 with last-block finish).
// All accumulation integer -> bit-deterministic.

#define NBINS   15
#define THREADS 256
#define CPT     4                    // classes per thread (float4)
#define TC      (THREADS * CPT)      // 1024 >= C
#define PSTRIDE (CPT * NBINS + 1)    // 61 (odd -> conflict-free banks)
#define LDSW    (THREADS * PSTRIDE)  // 15616 u32 = 62464 B -> 2 blocks/CU
#define SLAB    (TC * NBINS)         // 15360 i32 per chunk
#define NGROUP  16

__device__ __forceinline__ void bump(float v, unsigned* slot) {
    int b = (int)(v * 15.0f);                 // trunc==floor (v>=0) == ref ceil-1
    b = b < NBINS - 1 ? b : NBINS - 1;
    unsigned c = (unsigned)fmaf(v, 65536.0f, 0.5f);
    atomicAdd(&slot[b], (v > 0.0f) ? c : 0u); // ds_add_u32, thread-private slot
}

__global__ __launch_bounds__(THREADS, 2) void ece_hist(
    const float* __restrict__ probs, const int* __restrict__ labels,
    int N, int C, int R,
    int* __restrict__ partial)                // [chunks][SLAB] signed q16 sums
{
    __shared__ unsigned sA[LDSW];
    const int t = threadIdx.x;
    #pragma unroll
    for (int i = t; i < LDSW; i += THREADS) sA[i] = 0u;
    __syncthreads();

    const int chunk = blockIdx.x;
    const int cls0  = CPT * t;
    const int col   = (cls0 <= C - CPT) ? cls0 : (C - CPT) & ~3;  // 996, aligned

    const int r0 = chunk * R;
    int rend = N - r0; if (rend > R) rend = R; if (rend < 0) rend = 0;

    const float4* p = (const float4*)(probs + (size_t)r0 * C + col);
    const size_t rowstep = (size_t)(C >> 2);
    unsigned* s0 = sA + t * PSTRIDE;

    #pragma unroll 8
    for (int r = 0; r < rend; ++r) {
        float4 v = p[(size_t)r * rowstep];
        bump(v.x, s0);
        bump(v.y, s0 + NBINS);
        bump(v.z, s0 + 2 * NBINS);
        bump(v.w, s0 + 3 * NBINS);
    }

    // Correct events: subtract 65536 from the (label,bin) slot. Rows were just
    // streamed by this block -> L2-hot. ~R events per block total.
    for (int j = t; j < rend; j += THREADS) {
        int row = r0 + j;
        int lab = labels[row];
        if (lab >= 0 && lab < C) {
            float v = probs[(size_t)row * C + lab];
            if (v > 0.0f) {
                int b = (int)(v * 15.0f);
                b = b < NBINS - 1 ? b : NBINS - 1;
                atomicAdd(&sA[(lab >> 2) * PSTRIDE + (lab & 3) * NBINS + b],
                          (unsigned)(-65536));
            }
        }
    }
    __syncthreads();

    // Flush padded LDS -> linear class-major (coalesced stores).
    int* dst = partial + (size_t)chunk * SLAB;
    #pragma unroll
    for (int i = t; i < SLAB; i += THREADS) {
        int owner = i / (CPT * NBINS);
        int j = i - owner * (CPT * NBINS);
        dst[i] = (int)sA[owner * PSTRIDE + j];
    }
}

// Stage 1: per chunk-group signed partial sums (i32, exact). Also zeroes the
// red2 completion counter (stream-ordered before red2).
__global__ __launch_bounds__(256) void ece_red1(
    const int* __restrict__ partial, int chunks, int gsz,
    int* __restrict__ stage1, unsigned* __restrict__ counter)
{
    if (blockIdx.x == 0 && blockIdx.y == 0 && threadIdx.x == 0) *counter = 0u;
    int i = blockIdx.x * 256 + threadIdx.x;     // grid.x*256 == SLAB exactly
    int g = blockIdx.y;
    int k0 = g * gsz;
    int k1 = k0 + gsz; if (k1 > chunks) k1 = chunks;
    int s = 0;
    #pragma unroll 8
    for (int k = k0; k < k1; ++k)
        s += partial[(size_t)k * SLAB + i];
    stage1[(size_t)g * SLAB + i] = s;
}

// Stage 2: contrib = |sum_q16| / 65536 / N ; block sums -> last block finishes.
__global__ __launch_bounds__(256) void ece_red2(
    const int* __restrict__ stage1, int C, int N, int nb,
    float* __restrict__ blockSums, unsigned* __restrict__ counter,
    float* __restrict__ out)
{
    int i = blockIdx.x * 256 + threadIdx.x;
    float contrib = 0.0f;
    if (i < C * NBINS) {
        long long s = 0;
        #pragma unroll
        for (int g = 0; g < NGROUP; ++g)
            s += (long long)stage1[(size_t)g * SLAB + i];
        contrib = fabsf((float)s * (1.0f / 65536.0f)) * (1.0f / (float)N);
    }
    for (int o = 32; o; o >>= 1) contrib += __shfl_down(contrib, o);
    __shared__ float ws4[4];
    const int wid = threadIdx.x >> 6, lane = threadIdx.x & 63;
    if (lane == 0) ws4[wid] = contrib;
    __syncthreads();
    if (threadIdx.x == 0) {
        blockSums[blockIdx.x] = ws4[0] + ws4[1] + ws4[2] + ws4[3];
        __threadfence();
        unsigned old = atomicAdd(counter, 1u);
        if (old == (unsigned)(nb - 1)) {        // last block finishes
            __threadfence();
            double s = 0.0;
            for (int b = 0; b < nb; ++b) s += (double)blockSums[b];
            out[0] = (float)(s / (double)C);
        }
    }
}

extern "C" void kernel_launch(void* const* d_in, const int* in_sizes, int n_in,
                              void* d_out, int out_size, void* d_ws, size_t ws_size,
                              hipStream_t stream) {
    const float* probs  = (const float*)d_in[0];
    const int*   labels = (const int*)d_in[1];
    const int N = in_sizes[1];               // 100000
    const int C = in_sizes[0] / N;           // 1000

    // ws: [blockSums f32 x 128][counter u32] pad 4096 | stage1 i32[16][SLAB] | partials
    const size_t headBytes   = 4096;
    const size_t stage1Bytes = (size_t)NGROUP * SLAB * 4;   // 983 KB
    const size_t off_partial = headBytes + stage1Bytes;
    const size_t slabBytes   = (size_t)SLAB * 4;            // 61440

    float*    blockSums = (float*)d_ws;
    unsigned* counter   = (unsigned*)((char*)d_ws + 512);
    int*      stage1    = (int*)((char*)d_ws + headBytes);
    int*      partial   = (int*)((char*)d_ws + off_partial);

    long long avail = (long long)ws_size - (long long)off_partial;
    int chunks = (int)(avail / (long long)slabBytes);
    if (chunks > 500) chunks = 500;          // 500 blocks ~ 2/CU, all resident
    if (chunks < 2) chunks = 2;              // R<=65535 keeps q16 sum in i32
    const int R   = (N + chunks - 1) / chunks;
    const int gsz = (chunks + NGROUP - 1) / NGROUP;
    const int nb2 = (C * NBINS + 255) / 256; // 59 (<=128 blockSums slots)

    ece_hist<<<chunks, THREADS, 0, stream>>>(probs, labels, N, C, R, partial);
    dim3 r1grid(SLAB / 256, NGROUP);         // 60 x 16
    ece_red1<<<r1grid, 256, 0, stream>>>(partial, chunks, gsz, stage1, counter);
    ece_red2<<<nb2, 256, 0, stream>>>(stage1, C, N, nb2, blockSums, counter,
                                      (float*)d_out);
}

// Round 6
// 148.202 us; speedup vs baseline: 1.0445x; 1.0445x over previous
//
#include <hip/hip_runtime.h>

// Classwise ECE, probs [N=100000, C=1000] f32, labels [N] i32 -> scalar f32.
// R6: max-occupancy hist (32 waves/CU: 512 thr, 1 class/thread, stride-17
// LDS = 34 KB -> 4 blocks/CU). Correct-events fused as -65536 into signed
// q16 LDS conf slots; 3 dispatches; integer accumulation (deterministic).

#define NBINS   15
#define THREADS 512
#define TC      512                  // classes per tile (1 per thread)
#define TILES   2                    // covers C <= 1024
#define PSTRIDE 17                   // 15 bins + 2 pad (odd -> all 32 banks)
#define LDSW    (THREADS * PSTRIDE)  // 8704 u32 = 34816 B -> 4 blocks/CU
#define SLOTS   (TC * NBINS)         // 7680 per tile
#define SLAB    (TILES * SLOTS)      // 15360 i32 per chunk
#define NGROUP  16

__global__ __launch_bounds__(THREADS, 8) void ece_hist(
    const float* __restrict__ probs, const int* __restrict__ labels,
    int N, int C, int R,
    int* __restrict__ partial)                // [chunks][SLAB] signed q16 sums
{
    __shared__ unsigned sA[LDSW];
    const int t = threadIdx.x;
    #pragma unroll
    for (int i = t; i < LDSW; i += THREADS) sA[i] = 0u;
    __syncthreads();

    const int chunk = blockIdx.x;
    const int tile  = blockIdx.y;
    const int cls   = tile * TC + t;
    const int col   = (cls < C) ? cls : (C - 1);   // dead threads: slots unread

    const int r0 = chunk * R;
    int rend = N - r0; if (rend > R) rend = R; if (rend < 0) rend = 0;

    const float* p = probs + (size_t)r0 * C + col;
    unsigned* s0 = sA + t * PSTRIDE;

    #pragma unroll 8
    for (int r = 0; r < rend; ++r) {
        float v = p[(size_t)r * C];
        int b = (int)(v * 15.0f);            // trunc==floor (v>=0) == ref ceil-1
        b = b < NBINS - 1 ? b : NBINS - 1;
        unsigned c = (unsigned)fmaf(v, 65536.0f, 0.5f);
        atomicAdd(&s0[b], (v > 0.0f) ? c : 0u);   // ds_add_u32, private slot
    }

    // Correct events for labels inside this tile: subtract 65536 from the
    // (label,bin) slot. Addresses were just streamed by this block -> L2-hot.
    for (int j = t; j < rend; j += THREADS) {
        int row = r0 + j;
        int lab = labels[row];
        int lc  = lab - tile * TC;
        if (lc >= 0 && lc < TC && lab < C) {
            float v = probs[(size_t)row * C + lab];
            if (v > 0.0f) {
                int b = (int)(v * 15.0f);
                b = b < NBINS - 1 ? b : NBINS - 1;
                atomicAdd(&sA[lc * PSTRIDE + b], (unsigned)(-65536));
            }
        }
    }
    __syncthreads();

    // Flush padded LDS -> linear class-major (coalesced stores).
    int* dst = partial + (size_t)chunk * SLAB + (size_t)tile * SLOTS;
    #pragma unroll
    for (int i = t; i < SLOTS; i += THREADS) {
        int owner = i / NBINS, j = i - owner * NBINS;
        dst[i] = (int)sA[owner * PSTRIDE + j];
    }
}

// Stage 1: per chunk-group signed partial sums (i32, exact). Also zeroes the
// red2 completion counter (stream-ordered before red2).
__global__ __launch_bounds__(256) void ece_red1(
    const int* __restrict__ partial, int chunks, int gsz,
    int* __restrict__ stage1, unsigned* __restrict__ counter)
{
    if (blockIdx.x == 0 && blockIdx.y == 0 && threadIdx.x == 0) *counter = 0u;
    int i = blockIdx.x * 256 + threadIdx.x;     // grid.x*256 == SLAB exactly
    int g = blockIdx.y;
    int k0 = g * gsz;
    int k1 = k0 + gsz; if (k1 > chunks) k1 = chunks;
    int s = 0;
    #pragma unroll 8
    for (int k = k0; k < k1; ++k)
        s += partial[(size_t)k * SLAB + i];
    stage1[(size_t)g * SLAB + i] = s;
}

// Stage 2: contrib = |sum_q16| / 65536 / N ; last finishing block reduces.
__global__ __launch_bounds__(256) void ece_red2(
    const int* __restrict__ stage1, int C, int N, int nb,
    float* __restrict__ blockSums, unsigned* __restrict__ counter,
    float* __restrict__ out)
{
    int i = blockIdx.x * 256 + threadIdx.x;
    float contrib = 0.0f;
    if (i < C * NBINS) {
        long long s = 0;
        #pragma unroll
        for (int g = 0; g < NGROUP; ++g)
            s += (long long)stage1[(size_t)g * SLAB + i];
        contrib = fabsf((float)s * (1.0f / 65536.0f)) * (1.0f / (float)N);
    }
    for (int o = 32; o; o >>= 1) contrib += __shfl_down(contrib, o);
    __shared__ float ws4[4];
    const int wid = threadIdx.x >> 6, lane = threadIdx.x & 63;
    if (lane == 0) ws4[wid] = contrib;
    __syncthreads();
    if (threadIdx.x == 0) {
        blockSums[blockIdx.x] = ws4[0] + ws4[1] + ws4[2] + ws4[3];
        __threadfence();
        unsigned old = atomicAdd(counter, 1u);
        if (old == (unsigned)(nb - 1)) {
            __threadfence();
            double s = 0.0;
            for (int b = 0; b < nb; ++b) s += (double)blockSums[b];
            out[0] = (float)(s / (double)C);
        }
    }
}

extern "C" void kernel_launch(void* const* d_in, const int* in_sizes, int n_in,
                              void* d_out, int out_size, void* d_ws, size_t ws_size,
                              hipStream_t stream) {
    const float* probs  = (const float*)d_in[0];
    const int*   labels = (const int*)d_in[1];
    const int N = in_sizes[1];               // 100000
    const int C = in_sizes[0] / N;           // 1000

    // ws: [blockSums f32 x 128][counter u32] pad 4096 | stage1 i32[16][SLAB] | partials
    const size_t headBytes   = 4096;
    const size_t stage1Bytes = (size_t)NGROUP * SLAB * 4;   // 983 KB
    const size_t off_partial = headBytes + stage1Bytes;
    const size_t slabBytes   = (size_t)SLAB * 4;            // 61440

    float*    blockSums = (float*)d_ws;
    unsigned* counter   = (unsigned*)((char*)d_ws + 512);
    int*      stage1    = (int*)((char*)d_ws + headBytes);
    int*      partial   = (int*)((char*)d_ws + off_partial);

    long long avail = (long long)ws_size - (long long)off_partial;
    int chunks = (int)(avail / (long long)slabBytes);
    if (chunks > 512) chunks = 512;          // 512x2 tiles = 1024 blocks = 4/CU
    if (chunks < 2) chunks = 2;              // R<=65535 keeps q16 sum in i32
    const int R   = (N + chunks - 1) / chunks;
    const int gsz = (chunks + NGROUP - 1) / NGROUP;
    const int nb2 = (C * NBINS + 255) / 256; // 59 (<=128 blockSums slots)

    dim3 hgrid(chunks, TILES);
    ece_hist<<<hgrid, THREADS, 0, stream>>>(probs, labels, N, C, R, partial);
    dim3 r1grid(SLAB / 256, NGROUP);         // 60 x 16
    ece_red1<<<r1grid, 256, 0, stream>>>(partial, chunks, gsz, stage1, counter);
    ece_red2<<<nb2, 256, 0, stream>>>(stage1, C, N, nb2, blockSums, counter,
                                      (float*)d_out);
}